// Round 12
// baseline (3325.028 us; speedup 1.0000x reference)
//
#include <hip/hip_runtime.h>
#include <hip/hip_bf16.h>

#define DEV __device__ __forceinline__

typedef __bf16 bf16x8 __attribute__((ext_vector_type(8)));
typedef float  f32x4  __attribute__((ext_vector_type(4)));
typedef unsigned u32x4 __attribute__((ext_vector_type(4)));

constexpr int BB  = 512;   // batch
constexpr int TT  = 256;   // time steps
constexpr int DX  = 1024;
constexpr int DZ  = 256;
constexpr int DH  = 512;

DEV f32x4 mfma16(bf16x8 a, bf16x8 b, f32x4 c) {
    return __builtin_amdgcn_mfma_f32_16x16x32_bf16(a, b, c, 0, 0, 0);
}
DEV float sigf(float x) { return 1.0f / (1.0f + __expf(-x)); }
DEV float tanhf_(float x) {
    float e = __expf(-2.0f * fabsf(x));
    float r = (1.0f - e) / (1.0f + e);
    return copysignf(r, x);
}
DEV float softplusf(float x) {
    float m = fmaxf(x, 0.0f);
    return m + __logf(__expf(x - m) + __expf(-m));
}

// ---- all cross-block ops at device coherence point (sc0 sc1) — proven R5-R11 ----
DEV void st16_cc(void* p, bf16x8 v) {
    asm volatile("global_store_dwordx4 %0, %1, off sc0 sc1" :: "v"(p), "v"(v) : "memory");
}
DEV void st_flag(unsigned* p, unsigned v) {
    asm volatile("global_store_dword %0, %1, off sc0 sc1" :: "v"(p), "v"(v) : "memory");
}
// packed 4-dword flag poll: load + waitcnt fused in one asm (result guaranteed)
#define LDF4(dst, p) \
    asm volatile("global_load_dwordx4 %0, %1, off sc0 sc1\n\ts_waitcnt vmcnt(0)" \
                 : "=v"(dst) : "v"(p) : "memory")
#define VMCNT0 do { \
    asm volatile("s_waitcnt vmcnt(0)" ::: "memory"); \
    __builtin_amdgcn_sched_barrier(0); } while (0)
#define LGKM0 do { \
    asm volatile("s_waitcnt lgkmcnt(0)" ::: "memory"); \
    __builtin_amdgcn_sched_barrier(0); } while (0)

template <int N>
DEV void loadN(bf16x8* v, const char* p) {
    #pragma unroll
    for (int k = 0; k < N; ++k)
        asm volatile("global_load_dwordx4 %0, %1, off sc0 sc1" : "=v"(v[k]) : "v"(p + k * 64));
    VMCNT0;
}

// Flag layout per group (4KB, words): A-line wave w at +w*32 (16 dwords used);
// B-line at +128+w*32 (8 dwords); C-line at +256+w*32 (8 dwords). Producers
// store ONE dword of the shared line; consumers poll the LINE (1 request).
DEV void wait16s(const unsigned* line, unsigned tgt, int self) {
    const int lane = threadIdx.x & 63;
    const int seg = (lane & 3) * 4;
    const unsigned* p = line + seg;
    while (true) {
        u32x4 v; LDF4(v, p);
        bool ok = (v[0] >= tgt || seg + 0 == self) && (v[1] >= tgt || seg + 1 == self)
               && (v[2] >= tgt || seg + 2 == self) && (v[3] >= tgt || seg + 3 == self);
        if (__all((int)ok)) break;
    }
}
DEV void wait8s(const unsigned* line, unsigned tgt, int self) {
    const int lane = threadIdx.x & 63;
    const int seg = (lane & 1) * 4;
    const unsigned* p = line + seg;
    while (true) {
        u32x4 v; LDF4(v, p);
        bool ok = (v[0] >= tgt || seg + 0 == self) && (v[1] >= tgt || seg + 1 == self)
               && (v[2] >= tgt || seg + 2 == self) && (v[3] >= tgt || seg + 3 == self);
        if (__all((int)ok)) break;
    }
}
// consumer: all 4 A-lines (4 waves x 16 producers) >= tgt; throttled (slack ~2 steps)
DEV void cons_wait(const unsigned* gfl, unsigned tgt) {
    const int lane = threadIdx.x & 63;
    const unsigned* p = gfl + (lane & 3) * 32 + ((lane >> 2) & 3) * 4;
    while (true) {
        u32x4 v; LDF4(v, p);
        if (__all((int)(v[0] >= tgt && v[1] >= tgt && v[2] >= tgt && v[3] >= tgt))) break;
        __builtin_amdgcn_s_sleep(8);
    }
}

// ---------------- weight fp32 -> bf16 conversion + h0 broadcast staging ------
struct CvtArgs {
    const float* src[7];
    __bf16* dst[7];
    int n[7];
};
__global__ void cvt_weights(CvtArgs a, const float* h0, __bf16* h0buf) {
    int idx = blockIdx.x * blockDim.x + threadIdx.x;
    int stride = gridDim.x * blockDim.x;
    for (int s = 0; s < 7; ++s) {
        const float* sp = a.src[s];
        __bf16* dp = a.dst[s];
        int n = a.n[s];
        for (int i = idx; i < n; i += stride) dp[i] = (__bf16)sp[i];
    }
    for (int i = idx; i < 512 * 512; i += stride) h0buf[i] = (__bf16)h0[i & 511];
}

// ---------------- fused kernel: 256 blocks ----------------------------------
// blocks 0..191: weight-stationary recurrence. 8 groups x 24 blocks; r=bid>>3:
//   r<8 Z-block (hid+z, col-split 32), r>=8 G-block (gates, col-split 32).
//   Wave owns 16 rows; per-(block,wave) packed flags; no __syncthreads in loop.
//   Exchange in out[b][t] bytes [2048,4096): h' 1KB | hid 512B | z 512B.
// blocks 192..255: emitter consumers. Consumer c: group c&7, steps t=(c>>3)+8k.
//   Waits all flagA >= min(t+2,TT) ==> step-t exchange reads done ==> safe to
//   read h'(t) and overwrite row (b,t) with final x (clobbers exchange bytes).
__global__ __launch_bounds__(256, 1) void fused(
    const float* __restrict__ eps,
    const float* __restrict__ b1,  const float* __restrict__ bloc,
    const float* __restrict__ bscale, const float* __restrict__ bih,
    const float* __restrict__ bhh,
    const __bf16* __restrict__ wW1,   const __bf16* __restrict__ wWloc,
    const __bf16* __restrict__ wWscale, const __bf16* __restrict__ wWih,
    const __bf16* __restrict__ wWhh,
    const float* __restrict__ db1, const float* __restrict__ db2,
    const __bf16* __restrict__ dxW1, const __bf16* __restrict__ dxW2,
    const __bf16* __restrict__ h0buf,   // [512][512] bf16, prefilled
    unsigned* __restrict__ flags,       // 8 groups x 4KB packed flag lines
    char* __restrict__ outb)            // out bytes; row (b*TT+t)*4096
{
    __shared__ __bf16 lds[75776];   // 148 KB

    const int tid  = threadIdx.x;
    const int w    = tid >> 6;
    const int lane = tid & 63;
    const int r16  = lane & 15;
    const int g4   = lane >> 4;

    if (blockIdx.x < 192) {
        // ===================== recurrence blocks =====================
        const int g = blockIdx.x & 7;
        const int r = blockIdx.x >> 3;
        unsigned* gfl   = flags + g * 1024;       // words
        unsigned* lineA = gfl + w * 32;           // 16 dwords (G-blocks)
        unsigned* lineB = gfl + 128 + w * 32;     // 8 dwords (Z-blocks)
        unsigned* lineC = gfl + 256 + w * 32;     // 8 dwords (Z-blocks)
        const int rowW  = g * 64 + w * 16;

        auto stage = [&](const __bf16* src, __bf16* dst, int R, int C) {
            int chunks = R * C / 8;
            for (int ch = tid; ch < chunks; ch += 256) {
                int row = ch / (C / 8), cc = (ch % (C / 8)) * 8;
                bf16x8 v = *(const bf16x8*)(src + (size_t)row * C + cc);
                *(bf16x8*)(dst + ((row * C + cc) ^ ((row & 7) << 3))) = v;
            }
        };

        if (r < 8) {
            // ---------------- Z-block ----------------
            stage(wW1     + (size_t)(r * 32) * 512, lds,         32, 512);
            stage(wWloc   + (size_t)(r * 32) * 256, lds + 16384, 32, 256);
            stage(wWscale + (size_t)(r * 32) * 256, lds + 24576, 32, 256);
            __bf16* wb = lds + 32768 + w * 512;   // per-wave bounce [16][32]
            const int zc0 = r * 32;
            float bb1[2], bbl[2], bbs[2];
            #pragma unroll
            for (int tt = 0; tt < 2; ++tt) {
                int c = zc0 + tt * 16 + r16;
                bb1[tt] = b1[c]; bbl[tt] = bloc[c]; bbs[tt] = bscale[c];
            }
            __syncthreads();   // weights staged (only barrier)

            for (int t = 0; t < TT; ++t) {
                float ev[2][4];
                #pragma unroll
                for (int tt = 0; tt < 2; ++tt)
                    #pragma unroll
                    for (int i = 0; i < 4; ++i) {
                        int row = rowW + 4 * g4 + i;
                        ev[tt][i] = __builtin_nontemporal_load(
                            eps + ((size_t)row * TT + t) * DZ + zc0 + tt * 16 + r16);
                    }
                VMCNT0;
                if (t) wait16s(lineA, t, -1);
                const char* hp = (t == 0)
                    ? (const char*)(h0buf + (size_t)(rowW + r16) * 512) + g4 * 16
                    : outb + ((size_t)(rowW + r16) * TT + (t - 1)) * 4096 + 2048 + g4 * 16;
                bf16x8 hv[16];
                loadN<16>(hv, hp);
                // hid = relu(h @ W1^T + b1), own 32 cols
                f32x4 acc0 = {0,0,0,0}, acc1 = {0,0,0,0};
                #pragma unroll
                for (int kk = 0; kk < 16; ++kk) {
                    int l0 = r16, l1 = 16 + r16;
                    acc0 = mfma16(hv[kk], *(const bf16x8*)(lds + ((l0 * 512 + kk * 32 + g4 * 8) ^ ((l0 & 7) << 3))), acc0);
                    acc1 = mfma16(hv[kk], *(const bf16x8*)(lds + ((l1 * 512 + kk * 32 + g4 * 8) ^ ((l1 & 7) << 3))), acc1);
                }
                #pragma unroll
                for (int tt = 0; tt < 2; ++tt) {
                    f32x4 ac = tt ? acc1 : acc0;
                    #pragma unroll
                    for (int i = 0; i < 4; ++i)
                        wb[(4 * g4 + i) * 32 + tt * 16 + r16] = (__bf16)fmaxf(ac[i] + bb1[tt], 0.0f);
                }
                LGKM0;
                {
                    int rl = lane >> 2, ch = lane & 3;
                    bf16x8 v = *(const bf16x8*)(wb + rl * 32 + ch * 8);
                    st16_cc(outb + ((size_t)(rowW + rl) * TT + t) * 4096 + 3072 + (zc0 + ch * 8) * 2, v);
                }
                VMCNT0;   // data drained before flag
                if (lane == 0) st_flag(lineB + r, t + 1);
                wait8s(lineB, t + 1, r);
                // z = zloc + softplus(zscale) * eps (K = all 256 hid cols)
                const char* qp = outb + ((size_t)(rowW + r16) * TT + t) * 4096 + 3072 + g4 * 16;
                bf16x8 qv[8];
                loadN<8>(qv, qp);
                f32x4 aL0 = {0,0,0,0}, aL1 = {0,0,0,0}, aS0 = {0,0,0,0}, aS1 = {0,0,0,0};
                #pragma unroll
                for (int kk = 0; kk < 8; ++kk) {
                    int l0 = r16, l1 = 16 + r16;
                    int s0 = (l0 * 256 + kk * 32 + g4 * 8) ^ ((l0 & 7) << 3);
                    int s1 = (l1 * 256 + kk * 32 + g4 * 8) ^ ((l1 & 7) << 3);
                    aL0 = mfma16(qv[kk], *(const bf16x8*)(lds + 16384 + s0), aL0);
                    aL1 = mfma16(qv[kk], *(const bf16x8*)(lds + 16384 + s1), aL1);
                    aS0 = mfma16(qv[kk], *(const bf16x8*)(lds + 24576 + s0), aS0);
                    aS1 = mfma16(qv[kk], *(const bf16x8*)(lds + 24576 + s1), aS1);
                }
                #pragma unroll
                for (int tt = 0; tt < 2; ++tt) {
                    f32x4 L = tt ? aL1 : aL0, S = tt ? aS1 : aS0;
                    #pragma unroll
                    for (int i = 0; i < 4; ++i) {
                        float z = (L[i] + bbl[tt]) + softplusf(S[i] + bbs[tt]) * ev[tt][i];
                        wb[(4 * g4 + i) * 32 + tt * 16 + r16] = (__bf16)z;
                    }
                }
                LGKM0;
                {
                    int rl = lane >> 2, ch = lane & 3;
                    bf16x8 v = *(const bf16x8*)(wb + rl * 32 + ch * 8);
                    st16_cc(outb + ((size_t)(rowW + rl) * TT + t) * 4096 + 3584 + (zc0 + ch * 8) * 2, v);
                }
                VMCNT0;
                if (lane == 0) st_flag(lineC + r, t + 1);
            }
        } else {
            // ---------------- G-block ----------------
            const int c0 = (r - 8) * 32;
            for (int gg = 0; gg < 3; ++gg) {
                stage(wWhh + (size_t)(512 * gg + c0) * 512, lds + gg * 16384, 32, 512);
                stage(wWih + (size_t)(512 * gg + c0) * 256, lds + 49152 + gg * 8192, 32, 256);
            }
            __bf16* wb = lds + 73728 + w * 512;   // per-wave bounce [16][32]
            float bI[3][2], bH[3][2];
            #pragma unroll
            for (int gg = 0; gg < 3; ++gg)
                #pragma unroll
                for (int tt = 0; tt < 2; ++tt) {
                    int col = 512 * gg + c0 + tt * 16 + r16;
                    bI[gg][tt] = bih[col];
                    bH[gg][tt] = bhh[col];
                }
            float hreg[2][4];
            #pragma unroll
            for (int tt = 0; tt < 2; ++tt) {
                float v = (float)h0buf[c0 + tt * 16 + r16];
                #pragma unroll
                for (int i = 0; i < 4; ++i) hreg[tt][i] = v;
            }
            __syncthreads();   // weights staged (only barrier)

            for (int t = 0; t < TT; ++t) {
                if (t) wait16s(lineA, t, r - 8);
                const char* hp = (t == 0)
                    ? (const char*)(h0buf + (size_t)(rowW + r16) * 512) + g4 * 16
                    : outb + ((size_t)(rowW + r16) * TT + (t - 1)) * 4096 + 2048 + g4 * 16;
                bf16x8 hv[16];
                loadN<16>(hv, hp);
                // gh = h @ Whh_slice^T  (j = gate*2 + tt)
                f32x4 gh[6];
                #pragma unroll
                for (int j = 0; j < 6; ++j) gh[j] = (f32x4){0,0,0,0};
                #pragma unroll
                for (int kk = 0; kk < 16; ++kk) {
                    #pragma unroll
                    for (int j = 0; j < 6; ++j) {
                        int gg = j >> 1, lr = (j & 1) * 16 + r16;
                        gh[j] = mfma16(hv[kk], *(const bf16x8*)(lds + gg * 16384 +
                                  ((lr * 512 + kk * 32 + g4 * 8) ^ ((lr & 7) << 3))), gh[j]);
                    }
                }
                wait8s(lineC, t + 1, -1);
                const char* zp = outb + ((size_t)(rowW + r16) * TT + t) * 4096 + 3584 + g4 * 16;
                bf16x8 zv[8];
                loadN<8>(zv, zp);
                // gi = z @ Wih_slice^T
                f32x4 gi[6];
                #pragma unroll
                for (int j = 0; j < 6; ++j) gi[j] = (f32x4){0,0,0,0};
                #pragma unroll
                for (int kk = 0; kk < 8; ++kk) {
                    #pragma unroll
                    for (int j = 0; j < 6; ++j) {
                        int gg = j >> 1, lr = (j & 1) * 16 + r16;
                        gi[j] = mfma16(zv[kk], *(const bf16x8*)(lds + 49152 + gg * 8192 +
                                  ((lr * 256 + kk * 32 + g4 * 8) ^ ((lr & 7) << 3))), gi[j]);
                    }
                }
                // gates + h'
                #pragma unroll
                for (int tt = 0; tt < 2; ++tt) {
                    #pragma unroll
                    for (int i = 0; i < 4; ++i) {
                        float rr = sigf(gi[0 + tt][i] + bI[0][tt] + gh[0 + tt][i] + bH[0][tt]);
                        float uu = sigf(gi[2 + tt][i] + bI[1][tt] + gh[2 + tt][i] + bH[1][tt]);
                        float nn = tanhf_(gi[4 + tt][i] + bI[2][tt] + rr * (gh[4 + tt][i] + bH[2][tt]));
                        float hv2 = (1.0f - uu) * nn + uu * hreg[tt][i];
                        hreg[tt][i] = hv2;
                        wb[(4 * g4 + i) * 32 + tt * 16 + r16] = (__bf16)hv2;
                    }
                }
                LGKM0;
                {
                    int rl = lane >> 2, ch = lane & 3;
                    bf16x8 v = *(const bf16x8*)(wb + rl * 32 + ch * 8);
                    st16_cc(outb + ((size_t)(rowW + rl) * TT + t) * 4096 + 2048 + (c0 + ch * 8) * 2, v);
                }
                VMCNT0;
                if (lane == 0) st_flag(lineA + (r - 8), t + 1);
            }
        }
    } else {
        // ===================== emitter consumer blocks =====================
        const int c   = blockIdx.x - 192;   // 0..63
        const int g   = c & 7;
        const int ph  = c >> 3;             // 0..7: serves t = ph + 8k
        unsigned* gfl = flags + g * 1024;
        __bf16* hS   = lds;                 // [64][512] swizzled
        __bf16* hid2 = lds + 32768;         // [64][256] swizzled
        const int rowB = g * 64;

        for (int t = ph; t < TT; t += 8) {
            unsigned tgt = (t + 2 <= TT) ? (unsigned)(t + 2) : (unsigned)TT;
            if (tid < 64) cons_wait(gfl, tgt);
            __syncthreads();

            // stage h'(t) [64 rows x 512] -> LDS (sc0sc1: producer wrote far)
            {
                bf16x8 v[8];
                #pragma unroll
                for (int half = 0; half < 2; ++half) {
                    #pragma unroll
                    for (int it = 0; it < 8; ++it) {
                        int chunk = (half * 8 + it) * 256 + tid;   // 4096 chunks of 16B
                        int row = chunk >> 6, cc = (chunk & 63) * 8;
                        const char* p = outb + ((size_t)(rowB + row) * TT + t) * 4096 + 2048 + cc * 2;
                        asm volatile("global_load_dwordx4 %0, %1, off sc0 sc1" : "=v"(v[it]) : "v"(p));
                    }
                    VMCNT0;
                    #pragma unroll
                    for (int it = 0; it < 8; ++it) {
                        int chunk = (half * 8 + it) * 256 + tid;
                        int row = chunk >> 6, cc = (chunk & 63) * 8;
                        *(bf16x8*)(hS + ((row * 512 + cc) ^ ((row & 7) << 3))) = v[it];
                    }
                }
            }
            __syncthreads();

            {   // hid2 = relu(h @ dxW1^T + b1)  [64 x 256], K=512; waves split cols
                f32x4 acc[4][4];
                #pragma unroll
                for (int rt = 0; rt < 4; ++rt)
                    #pragma unroll
                    for (int ct = 0; ct < 4; ++ct) acc[rt][ct] = (f32x4){0,0,0,0};
                const __bf16* pB[4];
                #pragma unroll
                for (int ct = 0; ct < 4; ++ct)
                    pB[ct] = dxW1 + (w * 64 + 16 * ct + r16) * 512 + g4 * 8;
                #pragma unroll
                for (int kk = 0; kk < 16; ++kk) {
                    bf16x8 a[4];
                    #pragma unroll
                    for (int rt = 0; rt < 4; ++rt) {
                        int row = rt * 16 + r16;
                        a[rt] = *(const bf16x8*)(hS + ((row * 512 + kk * 32 + g4 * 8) ^ ((row & 7) << 3)));
                    }
                    #pragma unroll
                    for (int ct = 0; ct < 4; ++ct) {
                        bf16x8 b = *(const bf16x8*)(pB[ct] + kk * 32);
                        #pragma unroll
                        for (int rt = 0; rt < 4; ++rt)
                            acc[rt][ct] = mfma16(a[rt], b, acc[rt][ct]);
                    }
                }
                #pragma unroll
                for (int ct = 0; ct < 4; ++ct) {
                    int col = w * 64 + 16 * ct + r16;
                    float bias = db1[col];
                    #pragma unroll
                    for (int rt = 0; rt < 4; ++rt)
                        #pragma unroll
                        for (int i = 0; i < 4; ++i) {
                            int row = rt * 16 + g4 * 4 + i;
                            hid2[(row * 256 + col) ^ ((row & 7) << 3)] =
                                (__bf16)fmaxf(acc[rt][ct][i] + bias, 0.0f);
                        }
                }
            }
            __syncthreads();

            #pragma unroll
            for (int q = 0; q < 4; ++q) {   // x = sigmoid(hid2 @ dxW2^T + b2) [64 x 1024]
                f32x4 acc[4][4];
                #pragma unroll
                for (int rt = 0; rt < 4; ++rt)
                    #pragma unroll
                    for (int ct = 0; ct < 4; ++ct) acc[rt][ct] = (f32x4){0,0,0,0};
                const __bf16* pB[4];
                #pragma unroll
                for (int ct = 0; ct < 4; ++ct)
                    pB[ct] = dxW2 + (w * 256 + q * 64 + 16 * ct + r16) * 256 + g4 * 8;
                #pragma unroll
                for (int kk = 0; kk < 8; ++kk) {
                    bf16x8 a[4];
                    #pragma unroll
                    for (int rt = 0; rt < 4; ++rt) {
                        int row = rt * 16 + r16;
                        a[rt] = *(const bf16x8*)(hid2 + ((row * 256 + kk * 32 + g4 * 8) ^ ((row & 7) << 3)));
                    }
                    #pragma unroll
                    for (int ct = 0; ct < 4; ++ct) {
                        bf16x8 b = *(const bf16x8*)(pB[ct] + kk * 32);
                        #pragma unroll
                        for (int rt = 0; rt < 4; ++rt)
                            acc[rt][ct] = mfma16(a[rt], b, acc[rt][ct]);
                    }
                }
                #pragma unroll
                for (int ct = 0; ct < 4; ++ct) {
                    int col = w * 256 + q * 64 + 16 * ct + r16;
                    float bias = db2[col];
                    #pragma unroll
                    for (int rt = 0; rt < 4; ++rt)
                        #pragma unroll
                        for (int i = 0; i < 4; ++i) {
                            int row = rt * 16 + g4 * 4 + i;
                            float* dst = (float*)(outb + ((size_t)(rowB + row) * TT + t) * 4096) + col;
                            __builtin_nontemporal_store(sigf(acc[rt][ct][i] + bias), dst);
                        }
                }
            }
            __syncthreads();   // hid2/hS reads done before next tile staging
        }
    }
}

// ---------------- launch ----------------
extern "C" void kernel_launch(void* const* d_in, const int* in_sizes, int n_in,
                              void* d_out, int out_size, void* d_ws, size_t ws_size,
                              hipStream_t stream) {
    const float* eps       = (const float*)d_in[0];
    const float* dz_W1     = (const float*)d_in[1];
    const float* dz_b1     = (const float*)d_in[2];
    const float* dz_Wloc   = (const float*)d_in[3];
    const float* dz_bloc   = (const float*)d_in[4];
    const float* dz_Wscale = (const float*)d_in[5];
    const float* dz_bscale = (const float*)d_in[6];
    const float* gru_Wih   = (const float*)d_in[7];
    const float* gru_Whh   = (const float*)d_in[8];
    const float* gru_bih   = (const float*)d_in[9];
    const float* gru_bhh   = (const float*)d_in[10];
    const float* dx_W1     = (const float*)d_in[11];
    const float* dx_b1     = (const float*)d_in[12];
    const float* dx_W2     = (const float*)d_in[13];
    const float* dx_b2     = (const float*)d_in[14];
    const float* h0        = (const float*)d_in[15];
    float* out = (float*)d_out;
    char* ws = (char*)d_ws;

    __bf16* wW1     = (__bf16*)(ws + 0);
    __bf16* wWloc   = (__bf16*)(ws + 262144);
    __bf16* wWscale = (__bf16*)(ws + 393216);
    __bf16* wWih    = (__bf16*)(ws + 524288);
    __bf16* wWhh    = (__bf16*)(ws + 1310720);
    __bf16* wdxW1   = (__bf16*)(ws + 2883584);
    __bf16* wdxW2   = (__bf16*)(ws + 3145728);
    __bf16* h0buf   = (__bf16*)(ws + 3670016);   // 512x512 bf16
    unsigned* flags = (unsigned*)(ws + 4194304); // 8 groups x 4 KB packed lines

    hipMemsetAsync(flags, 0, 32768, stream);

    CvtArgs ca;
    ca.src[0] = dz_W1;     ca.dst[0] = wW1;     ca.n[0] = 256 * 512;
    ca.src[1] = dz_Wloc;   ca.dst[1] = wWloc;   ca.n[1] = 256 * 256;
    ca.src[2] = dz_Wscale; ca.dst[2] = wWscale; ca.n[2] = 256 * 256;
    ca.src[3] = gru_Wih;   ca.dst[3] = wWih;    ca.n[3] = 1536 * 256;
    ca.src[4] = gru_Whh;   ca.dst[4] = wWhh;    ca.n[4] = 1536 * 512;
    ca.src[5] = dx_W1;     ca.dst[5] = wdxW1;   ca.n[5] = 256 * 512;
    ca.src[6] = dx_W2;     ca.dst[6] = wdxW2;   ca.n[6] = 1024 * 256;

    cvt_weights<<<1024, 256, 0, stream>>>(ca, h0, h0buf);
    fused<<<256, 256, 0, stream>>>(eps, dz_b1, dz_bloc, dz_bscale,
                                   gru_bih, gru_bhh,
                                   wW1, wWloc, wWscale, wWih, wWhh,
                                   dx_b1, dx_b2, wdxW1, wdxW2,
                                   h0buf, flags, (char*)out);
}

// Round 13
// 2502.810 us; speedup vs baseline: 1.3285x; 1.3285x over previous
//
#include <hip/hip_runtime.h>
#include <hip/hip_bf16.h>

#define DEV __device__ __forceinline__

typedef __bf16 bf16x8 __attribute__((ext_vector_type(8)));
typedef float  f32x4  __attribute__((ext_vector_type(4)));

constexpr int BB  = 512;   // batch
constexpr int TT  = 256;   // time steps
constexpr int DX  = 1024;
constexpr int DZ  = 256;
constexpr int DH  = 512;

DEV f32x4 mfma16(bf16x8 a, bf16x8 b, f32x4 c) {
    return __builtin_amdgcn_mfma_f32_16x16x32_bf16(a, b, c, 0, 0, 0);
}
DEV float sigf(float x) { return 1.0f / (1.0f + __expf(-x)); }
DEV float tanhf_(float x) {
    float e = __expf(-2.0f * fabsf(x));
    float r = (1.0f - e) / (1.0f + e);
    return copysignf(r, x);
}
DEV float softplusf(float x) {
    float m = fmaxf(x, 0.0f);
    return m + __logf(__expf(x - m) + __expf(-m));
}

// ---- all cross-block ops at device coherence point (sc0 sc1) — proven R5-R11 ----
DEV void st16_cc(void* p, bf16x8 v) {
    asm volatile("global_store_dwordx4 %0, %1, off sc0 sc1" :: "v"(p), "v"(v) : "memory");
}
DEV void st_flag(unsigned* p, unsigned v) {
    asm volatile("global_store_dword %0, %1, off sc0 sc1" :: "v"(p), "v"(v) : "memory");
}
// issue-only flag load (no waitcnt)
#define LDI(dst, p) \
    asm volatile("global_load_dword %0, %1, off sc0 sc1" : "=v"(dst) : "v"(p) : "memory")
// wait until only the NEWEST vmem op is outstanding, then read vin (atomic asm)
DEV unsigned wait_older(unsigned vin) {
    unsigned vout;
    asm volatile("s_waitcnt vmcnt(1)\n\tv_mov_b32 %0, %1"
                 : "=v"(vout) : "v"(vin) : "memory");
    return vout;
}
#define VMCNT0 do { \
    asm volatile("s_waitcnt vmcnt(0)" ::: "memory"); \
    __builtin_amdgcn_sched_barrier(0); } while (0)
#define VMCNT8 do { \
    asm volatile("s_waitcnt vmcnt(8)" ::: "memory"); \
    __builtin_amdgcn_sched_barrier(0); } while (0)
#define VMCNT4 do { \
    asm volatile("s_waitcnt vmcnt(4)" ::: "memory"); \
    __builtin_amdgcn_sched_barrier(0); } while (0)
#define LGKM0 do { \
    asm volatile("s_waitcnt lgkmcnt(0)" ::: "memory"); \
    __builtin_amdgcn_sched_barrier(0); } while (0)

// issue-only data loads (caller inserts staged waitcnts)
template <int N>
DEV void issueN(bf16x8* v, const char* p) {
    #pragma unroll
    for (int k = 0; k < N; ++k)
        asm volatile("global_load_dwordx4 %0, %1, off sc0 sc1" : "=v"(v[k]) : "v"(p + k * 64));
}

// per-WAVE producer wait (R11-proven): per-producer 128B slots, double-poll.
DEV void wave_wait(const unsigned* f, int n, int w, unsigned tgt, int self) {
    const int lane = threadIdx.x & 63;
    const int slot = lane & (n - 1);
    const unsigned* p = f + ((slot * 4 + w) * 32);
    const int skip = (slot == self);
    VMCNT0;
    unsigned v0, v1;
    LDI(v0, p);
    while (true) {
        LDI(v1, p);
        if (__all(skip | (int)(wait_older(v0) >= tgt))) break;
        LDI(v0, p);
        if (__all(skip | (int)(wait_older(v1) >= tgt))) break;
    }
    VMCNT0;
}
// consumer wait: all 64 flagA slots of a group >= tgt; throttled (slack ~2 steps)
DEV void cons_wait(const unsigned* f, unsigned tgt) {
    const int lane = threadIdx.x & 63;
    const unsigned* p = f + lane * 32;
    while (true) {
        unsigned v;
        asm volatile("global_load_dword %0, %1, off sc0 sc1\n\ts_waitcnt vmcnt(0)"
                     : "=v"(v) : "v"(p) : "memory");
        if (__all((int)(v >= tgt))) break;
        __builtin_amdgcn_s_sleep(8);
    }
}

// ---------------- weight fp32 -> bf16 conversion + h0 broadcast staging ------
struct CvtArgs {
    const float* src[7];
    __bf16* dst[7];
    int n[7];
};
__global__ void cvt_weights(CvtArgs a, const float* h0, __bf16* h0buf) {
    int idx = blockIdx.x * blockDim.x + threadIdx.x;
    int stride = gridDim.x * blockDim.x;
    for (int s = 0; s < 7; ++s) {
        const float* sp = a.src[s];
        __bf16* dp = a.dst[s];
        int n = a.n[s];
        for (int i = idx; i < n; i += stride) dp[i] = (__bf16)sp[i];
    }
    for (int i = idx; i < 512 * 512; i += stride) h0buf[i] = (__bf16)h0[i & 511];
}

// ---------------- fused kernel: 256 blocks ----------------------------------
// blocks 0..191: weight-stationary recurrence. 8 groups x 24 blocks; r=bid>>3:
//   r<8 Z-block (hid+z, col-split 32), r>=8 G-block (gates, col-split 32).
//   Wave owns 16 rows; per-(block,wave) 128B flag slots; no __syncthreads in
//   loop. Exchange in out[b][t] bytes [2048,4096): h' 1KB | hid 512B | z 512B.
// blocks 192..255: emitter consumers. Consumer c: group c&7, steps t=(c>>3)+8k.
//   Waits all flagA >= min(t+2,TT) ==> step-t exchange reads done ==> safe to
//   read h'(t) and overwrite row (b,t) with final x (clobbers exchange bytes).
__global__ __launch_bounds__(256, 1) void fused(
    const float* __restrict__ eps,
    const float* __restrict__ b1,  const float* __restrict__ bloc,
    const float* __restrict__ bscale, const float* __restrict__ bih,
    const float* __restrict__ bhh,
    const __bf16* __restrict__ wW1,   const __bf16* __restrict__ wWloc,
    const __bf16* __restrict__ wWscale, const __bf16* __restrict__ wWih,
    const __bf16* __restrict__ wWhh,
    const float* __restrict__ db1, const float* __restrict__ db2,
    const __bf16* __restrict__ dxW1, const __bf16* __restrict__ dxW2,
    const __bf16* __restrict__ h0buf,   // [512][512] bf16, prefilled
    unsigned* __restrict__ flags,       // 8 groups x 16KB: A 64 | B 32 | C 32 x 128B
    char* __restrict__ outb)            // out bytes; row (b*TT+t)*4096
{
    __shared__ __bf16 lds[75776];   // 148 KB

    const int tid  = threadIdx.x;
    const int w    = tid >> 6;
    const int lane = tid & 63;
    const int r16  = lane & 15;
    const int g4   = lane >> 4;

    if (blockIdx.x < 192) {
        // ===================== recurrence blocks =====================
        const int g = blockIdx.x & 7;
        const int r = blockIdx.x >> 3;
        unsigned* gfl   = flags + g * 4096;
        unsigned* flagA = gfl;                   // 64 slots (16 G x 4 waves)
        unsigned* flagB = gfl + 2048;            // 32 slots (8 Z x 4)
        unsigned* flagC = gfl + 3072;            // 32 slots
        const int rowW  = g * 64 + w * 16;

        auto stage = [&](const __bf16* src, __bf16* dst, int R, int C) {
            int chunks = R * C / 8;
            for (int ch = tid; ch < chunks; ch += 256) {
                int row = ch / (C / 8), cc = (ch % (C / 8)) * 8;
                bf16x8 v = *(const bf16x8*)(src + (size_t)row * C + cc);
                *(bf16x8*)(dst + ((row * C + cc) ^ ((row & 7) << 3))) = v;
            }
        };

        if (r < 8) {
            // ---------------- Z-block ----------------
            stage(wW1     + (size_t)(r * 32) * 512, lds,         32, 512);
            stage(wWloc   + (size_t)(r * 32) * 256, lds + 16384, 32, 256);
            stage(wWscale + (size_t)(r * 32) * 256, lds + 24576, 32, 256);
            __bf16* wb = lds + 32768 + w * 512;   // per-wave bounce [16][32]
            const int zc0 = r * 32;
            float bb1[2], bbl[2], bbs[2];
            #pragma unroll
            for (int tt = 0; tt < 2; ++tt) {
                int c = zc0 + tt * 16 + r16;
                bb1[tt] = b1[c]; bbl[tt] = bloc[c]; bbs[tt] = bscale[c];
            }
            __syncthreads();   // weights staged (only barrier)

            for (int t = 0; t < TT; ++t) {
                float ev[2][4];
                #pragma unroll
                for (int tt = 0; tt < 2; ++tt)
                    #pragma unroll
                    for (int i = 0; i < 4; ++i) {
                        int row = rowW + 4 * g4 + i;
                        ev[tt][i] = __builtin_nontemporal_load(
                            eps + ((size_t)row * TT + t) * DZ + zc0 + tt * 16 + r16);
                    }
                if (t) wave_wait(flagA, 16, w, t, -1);
                const char* hp = (t == 0)
                    ? (const char*)(h0buf + (size_t)(rowW + r16) * 512) + g4 * 16
                    : outb + ((size_t)(rowW + r16) * TT + (t - 1)) * 4096 + 2048 + g4 * 16;
                bf16x8 hv[16];
                issueN<16>(hv, hp);
                // hid = relu(h @ W1^T + b1), own 32 cols — staged (8 | 8)
                f32x4 acc0 = {0,0,0,0}, acc1 = {0,0,0,0};
                VMCNT8;
                #pragma unroll
                for (int kk = 0; kk < 8; ++kk) {
                    int l0 = r16, l1 = 16 + r16;
                    acc0 = mfma16(hv[kk], *(const bf16x8*)(lds + ((l0 * 512 + kk * 32 + g4 * 8) ^ ((l0 & 7) << 3))), acc0);
                    acc1 = mfma16(hv[kk], *(const bf16x8*)(lds + ((l1 * 512 + kk * 32 + g4 * 8) ^ ((l1 & 7) << 3))), acc1);
                }
                VMCNT0;
                #pragma unroll
                for (int kk = 8; kk < 16; ++kk) {
                    int l0 = r16, l1 = 16 + r16;
                    acc0 = mfma16(hv[kk], *(const bf16x8*)(lds + ((l0 * 512 + kk * 32 + g4 * 8) ^ ((l0 & 7) << 3))), acc0);
                    acc1 = mfma16(hv[kk], *(const bf16x8*)(lds + ((l1 * 512 + kk * 32 + g4 * 8) ^ ((l1 & 7) << 3))), acc1);
                }
                #pragma unroll
                for (int tt = 0; tt < 2; ++tt) {
                    f32x4 ac = tt ? acc1 : acc0;
                    #pragma unroll
                    for (int i = 0; i < 4; ++i)
                        wb[(4 * g4 + i) * 32 + tt * 16 + r16] = (__bf16)fmaxf(ac[i] + bb1[tt], 0.0f);
                }
                LGKM0;   // wave-internal: bounce writes before packed reads
                {
                    int rl = lane >> 2, ch = lane & 3;
                    bf16x8 v = *(const bf16x8*)(wb + rl * 32 + ch * 8);
                    st16_cc(outb + ((size_t)(rowW + rl) * TT + t) * 4096 + 3072 + (zc0 + ch * 8) * 2, v);
                }
                VMCNT0;   // data drained before flag
                if (lane == 0) st_flag(flagB + (r * 4 + w) * 32, t + 1);
                wave_wait(flagB, 8, w, t + 1, r);
                // z = zloc + softplus(zscale) * eps (K = all 256 hid cols) — staged (4 | 4)
                const char* qp = outb + ((size_t)(rowW + r16) * TT + t) * 4096 + 3072 + g4 * 16;
                bf16x8 qv[8];
                issueN<8>(qv, qp);
                f32x4 aL0 = {0,0,0,0}, aL1 = {0,0,0,0}, aS0 = {0,0,0,0}, aS1 = {0,0,0,0};
                VMCNT4;
                #pragma unroll
                for (int kk = 0; kk < 4; ++kk) {
                    int l0 = r16, l1 = 16 + r16;
                    int s0 = (l0 * 256 + kk * 32 + g4 * 8) ^ ((l0 & 7) << 3);
                    int s1 = (l1 * 256 + kk * 32 + g4 * 8) ^ ((l1 & 7) << 3);
                    aL0 = mfma16(qv[kk], *(const bf16x8*)(lds + 16384 + s0), aL0);
                    aL1 = mfma16(qv[kk], *(const bf16x8*)(lds + 16384 + s1), aL1);
                    aS0 = mfma16(qv[kk], *(const bf16x8*)(lds + 24576 + s0), aS0);
                    aS1 = mfma16(qv[kk], *(const bf16x8*)(lds + 24576 + s1), aS1);
                }
                VMCNT0;
                #pragma unroll
                for (int kk = 4; kk < 8; ++kk) {
                    int l0 = r16, l1 = 16 + r16;
                    int s0 = (l0 * 256 + kk * 32 + g4 * 8) ^ ((l0 & 7) << 3);
                    int s1 = (l1 * 256 + kk * 32 + g4 * 8) ^ ((l1 & 7) << 3);
                    aL0 = mfma16(qv[kk], *(const bf16x8*)(lds + 16384 + s0), aL0);
                    aL1 = mfma16(qv[kk], *(const bf16x8*)(lds + 16384 + s1), aL1);
                    aS0 = mfma16(qv[kk], *(const bf16x8*)(lds + 24576 + s0), aS0);
                    aS1 = mfma16(qv[kk], *(const bf16x8*)(lds + 24576 + s1), aS1);
                }
                #pragma unroll
                for (int tt = 0; tt < 2; ++tt) {
                    f32x4 L = tt ? aL1 : aL0, S = tt ? aS1 : aS0;
                    #pragma unroll
                    for (int i = 0; i < 4; ++i) {
                        float z = (L[i] + bbl[tt]) + softplusf(S[i] + bbs[tt]) * ev[tt][i];
                        wb[(4 * g4 + i) * 32 + tt * 16 + r16] = (__bf16)z;
                    }
                }
                LGKM0;
                {
                    int rl = lane >> 2, ch = lane & 3;
                    bf16x8 v = *(const bf16x8*)(wb + rl * 32 + ch * 8);
                    st16_cc(outb + ((size_t)(rowW + rl) * TT + t) * 4096 + 3584 + (zc0 + ch * 8) * 2, v);
                }
                VMCNT0;
                if (lane == 0) st_flag(flagC + (r * 4 + w) * 32, t + 1);
            }
        } else {
            // ---------------- G-block ----------------
            const int c0 = (r - 8) * 32;
            for (int gg = 0; gg < 3; ++gg) {
                stage(wWhh + (size_t)(512 * gg + c0) * 512, lds + gg * 16384, 32, 512);
                stage(wWih + (size_t)(512 * gg + c0) * 256, lds + 49152 + gg * 8192, 32, 256);
            }
            __bf16* wb = lds + 73728 + w * 512;   // per-wave bounce [16][32]
            float bI[3][2], bH[3][2];
            #pragma unroll
            for (int gg = 0; gg < 3; ++gg)
                #pragma unroll
                for (int tt = 0; tt < 2; ++tt) {
                    int col = 512 * gg + c0 + tt * 16 + r16;
                    bI[gg][tt] = bih[col];
                    bH[gg][tt] = bhh[col];
                }
            float hreg[2][4];
            #pragma unroll
            for (int tt = 0; tt < 2; ++tt) {
                float v = (float)h0buf[c0 + tt * 16 + r16];
                #pragma unroll
                for (int i = 0; i < 4; ++i) hreg[tt][i] = v;
            }
            __syncthreads();   // weights staged (only barrier)

            for (int t = 0; t < TT; ++t) {
                if (t) wave_wait(flagA, 16, w, t, r - 8);
                const char* hp = (t == 0)
                    ? (const char*)(h0buf + (size_t)(rowW + r16) * 512) + g4 * 16
                    : outb + ((size_t)(rowW + r16) * TT + (t - 1)) * 4096 + 2048 + g4 * 16;
                bf16x8 hv[16];
                issueN<16>(hv, hp);
                // gh = h @ Whh_slice^T  (j = gate*2 + tt) — staged (8 | 8)
                f32x4 gh[6];
                #pragma unroll
                for (int j = 0; j < 6; ++j) gh[j] = (f32x4){0,0,0,0};
                VMCNT8;
                #pragma unroll
                for (int kk = 0; kk < 8; ++kk) {
                    #pragma unroll
                    for (int j = 0; j < 6; ++j) {
                        int gg = j >> 1, lr = (j & 1) * 16 + r16;
                        gh[j] = mfma16(hv[kk], *(const bf16x8*)(lds + gg * 16384 +
                                  ((lr * 512 + kk * 32 + g4 * 8) ^ ((lr & 7) << 3))), gh[j]);
                    }
                }
                VMCNT0;
                #pragma unroll
                for (int kk = 8; kk < 16; ++kk) {
                    #pragma unroll
                    for (int j = 0; j < 6; ++j) {
                        int gg = j >> 1, lr = (j & 1) * 16 + r16;
                        gh[j] = mfma16(hv[kk], *(const bf16x8*)(lds + gg * 16384 +
                                  ((lr * 512 + kk * 32 + g4 * 8) ^ ((lr & 7) << 3))), gh[j]);
                    }
                }
                wave_wait(flagC, 8, w, t + 1, -1);
                const char* zp = outb + ((size_t)(rowW + r16) * TT + t) * 4096 + 3584 + g4 * 16;
                bf16x8 zv[8];
                issueN<8>(zv, zp);
                // gi = z @ Wih_slice^T — staged (4 | 4)
                f32x4 gi[6];
                #pragma unroll
                for (int j = 0; j < 6; ++j) gi[j] = (f32x4){0,0,0,0};
                VMCNT4;
                #pragma unroll
                for (int kk = 0; kk < 4; ++kk) {
                    #pragma unroll
                    for (int j = 0; j < 6; ++j) {
                        int gg = j >> 1, lr = (j & 1) * 16 + r16;
                        gi[j] = mfma16(zv[kk], *(const bf16x8*)(lds + 49152 + gg * 8192 +
                                  ((lr * 256 + kk * 32 + g4 * 8) ^ ((lr & 7) << 3))), gi[j]);
                    }
                }
                VMCNT0;
                #pragma unroll
                for (int kk = 4; kk < 8; ++kk) {
                    #pragma unroll
                    for (int j = 0; j < 6; ++j) {
                        int gg = j >> 1, lr = (j & 1) * 16 + r16;
                        gi[j] = mfma16(zv[kk], *(const bf16x8*)(lds + 49152 + gg * 8192 +
                                  ((lr * 256 + kk * 32 + g4 * 8) ^ ((lr & 7) << 3))), gi[j]);
                    }
                }
                // gates + h'
                #pragma unroll
                for (int tt = 0; tt < 2; ++tt) {
                    #pragma unroll
                    for (int i = 0; i < 4; ++i) {
                        float rr = sigf(gi[0 + tt][i] + bI[0][tt] + gh[0 + tt][i] + bH[0][tt]);
                        float uu = sigf(gi[2 + tt][i] + bI[1][tt] + gh[2 + tt][i] + bH[1][tt]);
                        float nn = tanhf_(gi[4 + tt][i] + bI[2][tt] + rr * (gh[4 + tt][i] + bH[2][tt]));
                        float hv2 = (1.0f - uu) * nn + uu * hreg[tt][i];
                        hreg[tt][i] = hv2;
                        wb[(4 * g4 + i) * 32 + tt * 16 + r16] = (__bf16)hv2;
                    }
                }
                LGKM0;
                {
                    int rl = lane >> 2, ch = lane & 3;
                    bf16x8 v = *(const bf16x8*)(wb + rl * 32 + ch * 8);
                    st16_cc(outb + ((size_t)(rowW + rl) * TT + t) * 4096 + 2048 + (c0 + ch * 8) * 2, v);
                }
                VMCNT0;
                if (lane == 0) st_flag(flagA + ((r - 8) * 4 + w) * 32, t + 1);
            }
        }
    } else {
        // ===================== emitter consumer blocks =====================
        const int c   = blockIdx.x - 192;   // 0..63
        const int g   = c & 7;
        const int ph  = c >> 3;             // 0..7: serves t = ph + 8k
        unsigned* flagA = flags + g * 4096;
        __bf16* hS   = lds;                 // [64][512] swizzled
        __bf16* hid2 = lds + 32768;         // [64][256] swizzled
        const int rowB = g * 64;

        for (int t = ph; t < TT; t += 8) {
            unsigned tgt = (t + 2 <= TT) ? (unsigned)(t + 2) : (unsigned)TT;
            if (tid < 64) cons_wait(flagA, tgt);
            __syncthreads();

            // stage h'(t) [64 rows x 512] -> LDS (sc0sc1: producer wrote far)
            {
                bf16x8 v[8];
                #pragma unroll
                for (int half = 0; half < 2; ++half) {
                    #pragma unroll
                    for (int it = 0; it < 8; ++it) {
                        int chunk = (half * 8 + it) * 256 + tid;   // 4096 chunks of 16B
                        int row = chunk >> 6, cc = (chunk & 63) * 8;
                        const char* p = outb + ((size_t)(rowB + row) * TT + t) * 4096 + 2048 + cc * 2;
                        asm volatile("global_load_dwordx4 %0, %1, off sc0 sc1" : "=v"(v[it]) : "v"(p));
                    }
                    VMCNT0;
                    #pragma unroll
                    for (int it = 0; it < 8; ++it) {
                        int chunk = (half * 8 + it) * 256 + tid;
                        int row = chunk >> 6, cc = (chunk & 63) * 8;
                        *(bf16x8*)(hS + ((row * 512 + cc) ^ ((row & 7) << 3))) = v[it];
                    }
                }
            }
            __syncthreads();

            {   // hid2 = relu(h @ dxW1^T + b1)  [64 x 256], K=512; waves split cols
                f32x4 acc[4][4];
                #pragma unroll
                for (int rt = 0; rt < 4; ++rt)
                    #pragma unroll
                    for (int ct = 0; ct < 4; ++ct) acc[rt][ct] = (f32x4){0,0,0,0};
                const __bf16* pB[4];
                #pragma unroll
                for (int ct = 0; ct < 4; ++ct)
                    pB[ct] = dxW1 + (w * 64 + 16 * ct + r16) * 512 + g4 * 8;
                #pragma unroll
                for (int kk = 0; kk < 16; ++kk) {
                    bf16x8 a[4];
                    #pragma unroll
                    for (int rt = 0; rt < 4; ++rt) {
                        int row = rt * 16 + r16;
                        a[rt] = *(const bf16x8*)(hS + ((row * 512 + kk * 32 + g4 * 8) ^ ((row & 7) << 3)));
                    }
                    #pragma unroll
                    for (int ct = 0; ct < 4; ++ct) {
                        bf16x8 b = *(const bf16x8*)(pB[ct] + kk * 32);
                        #pragma unroll
                        for (int rt = 0; rt < 4; ++rt)
                            acc[rt][ct] = mfma16(a[rt], b, acc[rt][ct]);
                    }
                }
                #pragma unroll
                for (int ct = 0; ct < 4; ++ct) {
                    int col = w * 64 + 16 * ct + r16;
                    float bias = db1[col];
                    #pragma unroll
                    for (int rt = 0; rt < 4; ++rt)
                        #pragma unroll
                        for (int i = 0; i < 4; ++i) {
                            int row = rt * 16 + g4 * 4 + i;
                            hid2[(row * 256 + col) ^ ((row & 7) << 3)] =
                                (__bf16)fmaxf(acc[rt][ct][i] + bias, 0.0f);
                        }
                }
            }
            __syncthreads();

            #pragma unroll
            for (int q = 0; q < 4; ++q) {   // x = sigmoid(hid2 @ dxW2^T + b2) [64 x 1024]
                f32x4 acc[4][4];
                #pragma unroll
                for (int rt = 0; rt < 4; ++rt)
                    #pragma unroll
                    for (int ct = 0; ct < 4; ++ct) acc[rt][ct] = (f32x4){0,0,0,0};
                const __bf16* pB[4];
                #pragma unroll
                for (int ct = 0; ct < 4; ++ct)
                    pB[ct] = dxW2 + (w * 256 + q * 64 + 16 * ct + r16) * 256 + g4 * 8;
                #pragma unroll
                for (int kk = 0; kk < 8; ++kk) {
                    bf16x8 a[4];
                    #pragma unroll
                    for (int rt = 0; rt < 4; ++rt) {
                        int row = rt * 16 + r16;
                        a[rt] = *(const bf16x8*)(hid2 + ((row * 256 + kk * 32 + g4 * 8) ^ ((row & 7) << 3)));
                    }
                    #pragma unroll
                    for (int ct = 0; ct < 4; ++ct) {
                        bf16x8 b = *(const bf16x8*)(pB[ct] + kk * 32);
                        #pragma unroll
                        for (int rt = 0; rt < 4; ++rt)
                            acc[rt][ct] = mfma16(a[rt], b, acc[rt][ct]);
                    }
                }
                #pragma unroll
                for (int ct = 0; ct < 4; ++ct) {
                    int col = w * 256 + q * 64 + 16 * ct + r16;
                    float bias = db2[col];
                    #pragma unroll
                    for (int rt = 0; rt < 4; ++rt)
                        #pragma unroll
                        for (int i = 0; i < 4; ++i) {
                            int row = rt * 16 + g4 * 4 + i;
                            float* dst = (float*)(outb + ((size_t)(rowB + row) * TT + t) * 4096) + col;
                            __builtin_nontemporal_store(sigf(acc[rt][ct][i] + bias), dst);
                        }
                }
            }
            __syncthreads();   // hid2/hS reads done before next tile staging
        }
    }
}

// ---------------- launch ----------------
extern "C" void kernel_launch(void* const* d_in, const int* in_sizes, int n_in,
                              void* d_out, int out_size, void* d_ws, size_t ws_size,
                              hipStream_t stream) {
    const float* eps       = (const float*)d_in[0];
    const float* dz_W1     = (const float*)d_in[1];
    const float* dz_b1     = (const float*)d_in[2];
    const float* dz_Wloc   = (const float*)d_in[3];
    const float* dz_bloc   = (const float*)d_in[4];
    const float* dz_Wscale = (const float*)d_in[5];
    const float* dz_bscale = (const float*)d_in[6];
    const float* gru_Wih   = (const float*)d_in[7];
    const float* gru_Whh   = (const float*)d_in[8];
    const float* gru_bih   = (const float*)d_in[9];
    const float* gru_bhh   = (const float*)d_in[10];
    const float* dx_W1     = (const float*)d_in[11];
    const float* dx_b1     = (const float*)d_in[12];
    const float* dx_W2     = (const float*)d_in[13];
    const float* dx_b2     = (const float*)d_in[14];
    const float* h0        = (const float*)d_in[15];
    float* out = (float*)d_out;
    char* ws = (char*)d_ws;

    __bf16* wW1     = (__bf16*)(ws + 0);
    __bf16* wWloc   = (__bf16*)(ws + 262144);
    __bf16* wWscale = (__bf16*)(ws + 393216);
    __bf16* wWih    = (__bf16*)(ws + 524288);
    __bf16* wWhh    = (__bf16*)(ws + 1310720);
    __bf16* wdxW1   = (__bf16*)(ws + 2883584);
    __bf16* wdxW2   = (__bf16*)(ws + 3145728);
    __bf16* h0buf   = (__bf16*)(ws + 3670016);   // 512x512 bf16
    unsigned* flags = (unsigned*)(ws + 4194304); // 8 groups x 16 KB = 128 KB

    hipMemsetAsync(flags, 0, 131072, stream);

    CvtArgs ca;
    ca.src[0] = dz_W1;     ca.dst[0] = wW1;     ca.n[0] = 256 * 512;
    ca.src[1] = dz_Wloc;   ca.dst[1] = wWloc;   ca.n[1] = 256 * 256;
    ca.src[2] = dz_Wscale; ca.dst[2] = wWscale; ca.n[2] = 256 * 256;
    ca.src[3] = gru_Wih;   ca.dst[3] = wWih;    ca.n[3] = 1536 * 256;
    ca.src[4] = gru_Whh;   ca.dst[4] = wWhh;    ca.n[4] = 1536 * 512;
    ca.src[5] = dx_W1;     ca.dst[5] = wdxW1;   ca.n[5] = 256 * 512;
    ca.src[6] = dx_W2;     ca.dst[6] = wdxW2;   ca.n[6] = 1024 * 256;

    cvt_weights<<<1024, 256, 0, stream>>>(ca, h0, h0buf);
    fused<<<256, 256, 0, stream>>>(eps, dz_b1, dz_bloc, dz_bscale,
                                   gru_bih, gru_bhh,
                                   wW1, wWloc, wWscale, wWih, wWhh,
                                   dx_b1, dx_b2, wdxW1, wdxW2,
                                   h0buf, flags, (char*)out);
}